// Round 14
// baseline (162.626 us; speedup 1.0000x reference)
//
#include <hip/hip_runtime.h>

#define NB 256
#define IN_F 16
#define NGP 4

// ---------------- compile-time algebra tables (NATURAL blade order: idx=mask) ----
namespace alg {
constexpr int popc(int x){int c=0;while(x){c+=x&1;x>>=1;}return c;}
constexpr int qt(int m){return popc(m)&3;}
constexpr int sgn(int a,int b){int s=0;int t=a>>1;while(t){s+=popc(t&b);t>>=1;}return s&1;}
struct Tab {
  unsigned char w[64][64];   // [i][j] -> qt(i)*16 + qt(j)*4 + qt(i^j)
  unsigned char s[64][64];   // [i][j] -> sign of e_i * e_(i^j)
};
constexpr Tab build(){
  Tab t{};
  for(int i=0;i<64;++i)for(int j=0;j<64;++j){
    int k=i^j;
    t.w[i][j]=(unsigned char)(qt(i)*16+qt(j)*4+qt(k));
    t.s[i][j]=(unsigned char)sgn(i,k);
  }
  return t;
}
constexpr Tab T = build();
}

// ---------------- prep: transpose weights into workspace (coalesced READS) ----
// lw_t[((l*4+c)*64+m)*64+f] = gp_lin_w[((l*64+f)*64+m)*4+c]   (65536 floats)
// gpw_t[(l*64+widx)*64+f]   = gp_w[(l*64+f)*64+widx]          (16384 floats)
// w1t [f2*64+f]             = mlp_w1[f*64+f2]                 ( 4096 floats)
__global__ void ga_prep(const float* __restrict__ gp_lin_w,
                        const float* __restrict__ gp_w,
                        const float* __restrict__ mlp_w1,
                        float* __restrict__ lw_t, float* __restrict__ gpw_t,
                        float* __restrict__ w1t,
                        float* __restrict__ out) {
  const int bx = blockIdx.x, t = threadIdx.x;
  if (bx == 0 && t == 0) out[0] = 0.f;   // mean accumulator init
  if (bx < 256) {
    const int l = bx >> 6, f = bx & 63;
    const int m = t >> 2, c = t & 3;
    lw_t[((l*4+c)*64 + m)*64 + f] = gp_lin_w[bx*256 + t];
  } else if (bx < 320) {
    const int b2 = bx - 256;
    const int l = b2 >> 4, f0 = (b2 & 15) * 4;
    const int f = f0 + (t >> 6), k = t & 63;
    gpw_t[(l*64 + k)*64 + f] = gp_w[(l*64 + f0)*64 + t];
  } else {
    const int o = (bx - 320)*256 + t;
    const int f = o >> 6, f2 = o & 63;
    w1t[f2*64 + f] = mlp_w1[o];
  }
}

// ---------------- GP: interleaved j-octet over ic-pairs; all indices static ----
// x4/y4: [quad q][channel f][sub s]. (8p+a)^(8JO+b) = 8(p^JO)+(a^b) etc., so
// the pair {ic=2p, 2p+1} x both j-quads needs only y-quads {2(p^JO), +1}:
// 4 b128 reads feed 128 FMAs (the per-thread LDS-read floor). wv PRE-SCALED.
// FULLY unrolled: wv/acc indices must stay compile-time (R6/R12 law — any
// runtime index demotes the private array to scratch, ~200 MB WRITE_SIZE).
template<int JO>
__device__ __forceinline__ void gp_oct2(const float* __restrict__ x4,
    const float* __restrict__ y4, const float (&wv)[64], int f, float (&acc)[8]) {
  #pragma unroll
  for (int p = 0; p < 8; ++p) {
    const int r0 = 2*(p^JO);
    const float4 xv0 = *(const float4*)(x4 + ((2*p  )*64 + f)*4);
    const float4 xv1 = *(const float4*)(x4 + ((2*p+1)*64 + f)*4);
    const float4 yv0 = *(const float4*)(y4 + ((r0   )*64 + f)*4);
    const float4 yv1 = *(const float4*)(y4 + ((r0+1 )*64 + f)*4);
    const float x0[4] = {xv0.x,xv0.y,xv0.z,xv0.w};
    const float x1[4] = {xv1.x,xv1.y,xv1.z,xv1.w};
    const float y0[4] = {yv0.x,yv0.y,yv0.z,yv0.w};
    const float y1[4] = {yv1.x,yv1.y,yv1.z,yv1.w};
    #pragma unroll
    for (int b = 0; b < 4; ++b) {
      #pragma unroll
      for (int a = 0; a < 4; ++a) {
        const int i0 = 8*p + a, i1 = 8*p + 4 + a;
        const int j0 = 8*JO + b, j1 = 8*JO + 4 + b;
        float tp;
        tp = wv[alg::T.w[i0][j0]] * y0[a^b];   // k-quad r0
        acc[b]   = alg::T.s[i0][j0] ? fmaf(-tp, x0[a], acc[b])   : fmaf(tp, x0[a], acc[b]);
        tp = wv[alg::T.w[i1][j0]] * y1[a^b];   // k-quad r0+1
        acc[b]   = alg::T.s[i1][j0] ? fmaf(-tp, x1[a], acc[b])   : fmaf(tp, x1[a], acc[b]);
        tp = wv[alg::T.w[i0][j1]] * y1[a^b];   // k-quad r0+1
        acc[4+b] = alg::T.s[i0][j1] ? fmaf(-tp, x0[a], acc[4+b]) : fmaf(tp, x0[a], acc[4+b]);
        tp = wv[alg::T.w[i1][j1]] * y0[a^b];   // k-quad r0
        acc[4+b] = alg::T.s[i1][j1] ? fmaf(-tp, x1[a], acc[4+b]) : fmaf(tp, x1[a], acc[4+b]);
      }
    }
  }
}

// ---------------- main fused kernel: TWO 512-thread blocks per batch element ----
// Grid 512 = 2 redundant blocks per element (b = bx & 255); only bx<256 writes.
// Rationale: the algebra forces 64 channels/block (wave-uniform j templates) and
// B=256 gives 1 block/CU at grid 256 -> 2 waves/SIMD, ~60% stall. Two identical
// blocks/CU (2x58 KB = 116 KB < 160 KB LDS; 4 waves/SIMD x 128 VGPR = full file)
// let each block's barrier drain overlap the twin's issue. Compiler view is
// unchanged -> same 128-VGPR budget (LDS 57984 B in the (53.3,80) KB window).
// Unroll law (R6/R12): loops indexing private arrays with the loop counter
// (norm s4, wv build, GP) must be FULLY unrolled.
__global__ __launch_bounds__(512) void ga_main(
    const float* __restrict__ points, const float* __restrict__ products,
    const float* __restrict__ lin_w,  const float* __restrict__ lin_b,
    const float* __restrict__ gp_a,
    const float* __restrict__ mlp_b1,
    const float* __restrict__ mlp_w2, const float* __restrict__ mlp_b2,
    const float* __restrict__ lw_t,   const float* __restrict__ gpw_t,
    const float* __restrict__ w1t,
    float* __restrict__ d_out)
{
  __shared__ __align__(16) float xA[16*64*4];  // state buf A [quad][f][sub] (16384 B)
  __shared__ __align__(16) float xB[16*64*4];  // state buf B               (16384 B)
  __shared__ __align__(16) float y4[16*64*4];  // lin out    [quad][f][sub] (16384 B)
  __shared__ float red[4*8*64];                // tail partials              (8192 B)
  __shared__ float pts[96];                    //                            ( 384 B)
  __shared__ float ynrm[64];                   //                            ( 256 B)

  const int t  = threadIdx.x;
  const int b  = blockIdx.x & 255;             // element (2 blocks per element)
  const bool wr = (blockIdx.x < 256);          // twin selector: only one writes
  const int f  = t & 63;
  const int jo = t >> 6;                       // 0..7, wave-uniform
  const int qb = __builtin_popcount((unsigned)jo) & 3;

  for (int i = t; i < 16*64*4; i += 512) xA[i] = 0.f;
  if (t < 96) pts[t] = points[b*96 + t];
  __syncthreads();

  // phase 0: embed grade-1 + first qt-linear (blades {0,1,2,4,8,16,32} nonzero)
  if (t < 64) {
    float a[6] = {0,0,0,0,0,0};
    for (int m = 0; m < IN_F; ++m) {
      float lw = lin_w[(t*IN_F+m)*4 + 1];   // qt(grade1)=1
      #pragma unroll
      for (int g = 0; g < 6; ++g) a[g] = fmaf(pts[m*6+g], lw, a[g]);
    }
    xA[(0*64+t)*4+0] = lin_b[t];   // blade 0
    xA[(0*64+t)*4+1] = a[0];       // blade 1
    xA[(0*64+t)*4+2] = a[1];       // blade 2
    xA[(1*64+t)*4+0] = a[2];       // blade 4
    xA[(2*64+t)*4+0] = a[3];       // blade 8
    xA[(4*64+t)*4+0] = a[4];       // blade 16
    xA[(8*64+t)*4+0] = a[5];       // blade 32
  }
  __syncthreads();

  float acc[8];

  for (int l = 0; l < NGP; ++l) {
    const float* xin  = (l & 1) ? xB : xA;
    float*       xout = (l & 1) ? xA : xB;

    // ---- qt-linear: 8 outputs/thread (j = 8*jo+d); classes qb+{0,1,1,2,1,2,2,3}
    {
      float lacc[8] = {0,0,0,0,0,0,0,0};
      const float* pA = lw_t + (l*4 + ((qb+0)&3))*4096 + f;
      const float* pB = lw_t + (l*4 + ((qb+1)&3))*4096 + f;
      const float* pC = lw_t + (l*4 + ((qb+2)&3))*4096 + f;
      const float* pD = lw_t + (l*4 + ((qb+3)&3))*4096 + f;
      #pragma unroll 8
      for (int m = 0; m < 64; ++m) {
        const float4 xq0 = *(const float4*)(xin + ((2*jo  )*64 + m)*4); // broadcast
        const float4 xq1 = *(const float4*)(xin + ((2*jo+1)*64 + m)*4); // broadcast
        const float wA = pA[m*64], wB = pB[m*64], wC = pC[m*64], wD = pD[m*64];
        lacc[0] = fmaf(wA, xq0.x, lacc[0]);
        lacc[1] = fmaf(wB, xq0.y, lacc[1]);
        lacc[2] = fmaf(wB, xq0.z, lacc[2]);
        lacc[3] = fmaf(wC, xq0.w, lacc[3]);
        lacc[4] = fmaf(wB, xq1.x, lacc[4]);
        lacc[5] = fmaf(wC, xq1.y, lacc[5]);
        lacc[6] = fmaf(wC, xq1.z, lacc[6]);
        lacc[7] = fmaf(wD, xq1.w, lacc[7]);
      }
      // y-store (b128, RAW — normalization folded into wv later)
      *(float4*)(y4 + ((2*jo  )*64 + f)*4) = make_float4(lacc[0],lacc[1],lacc[2],lacc[3]);
      *(float4*)(y4 + ((2*jo+1)*64 + f)*4) = make_float4(lacc[4],lacc[5],lacc[6],lacc[7]);
    }
    __syncthreads();   // B1: y4 complete

    // ---- self-computed norms (redundant per thread; no reduction barriers) ----
    // FULLY unrolled: qc must be compile-time (s4 indexing).
    float iv[4];
    {
      float s4[4] = {0.f, 0.f, 0.f, 0.f};
      #pragma unroll
      for (int q = 0; q < 16; ++q) {
        const float4 yv = *(const float4*)(y4 + (q*64 + f)*4);
        const int qc = alg::popc(q) & 3;   // compile-time per unrolled q
        s4[(qc+0)&3] = fmaf(yv.x, yv.x, s4[(qc+0)&3]);
        s4[(qc+1)&3] = fmaf(yv.y, yv.y, s4[(qc+1)&3]);
        s4[(qc+1)&3] = fmaf(yv.z, yv.z, s4[(qc+1)&3]);
        s4[(qc+2)&3] = fmaf(yv.w, yv.w, s4[(qc+2)&3]);
      }
      #pragma unroll
      for (int c = 0; c < 4; ++c) {
        const float nrm = sqrtf(fmaxf(s4[c], 1e-12f));
        const float av  = gp_a[(l*64+f)*4 + c];
        const float sig = 1.f/(1.f + expf(-av));
        const float nn  = sig*(nrm-1.f) + 1.f;
        iv[c] = 1.f/(nn + 1e-6f);
      }
    }

    // ---- weight table: coalesced b32 loads, PRE-SCALED by invn (qk = wi&3) ----
    float wv[64];
    {
      const float* gw = gpw_t + l*4096 + f;   // [widx][f], coalesced
      #pragma unroll
      for (int wq = 0; wq < 16; ++wq) {
        wv[wq*4+0] = gw[(wq*4+0)*64] * iv[0];
        wv[wq*4+1] = gw[(wq*4+1)*64] * iv[1];
        wv[wq*4+2] = gw[(wq*4+2)*64] * iv[2];
        wv[wq*4+3] = gw[(wq*4+3)*64] * iv[3];
      }
    }

    // ---- geometric product: interleaved octet, writes the OTHER x buffer ----
    #pragma unroll
    for (int ii = 0; ii < 8; ++ii) acc[ii] = 0.f;
    switch (jo) {
      case 0: gp_oct2<0>(xin, y4, wv, f, acc); break;
      case 1: gp_oct2<1>(xin, y4, wv, f, acc); break;
      case 2: gp_oct2<2>(xin, y4, wv, f, acc); break;
      case 3: gp_oct2<3>(xin, y4, wv, f, acc); break;
      case 4: gp_oct2<4>(xin, y4, wv, f, acc); break;
      case 5: gp_oct2<5>(xin, y4, wv, f, acc); break;
      case 6: gp_oct2<6>(xin, y4, wv, f, acc); break;
      default: gp_oct2<7>(xin, y4, wv, f, acc); break;
    }
    if (l < NGP-1) {
      *(float4*)(xout + ((2*jo  )*64 + f)*4) = make_float4(acc[0],acc[1],acc[2],acc[3]);
      *(float4*)(xout + ((2*jo+1)*64 + f)*4) = make_float4(acc[4],acc[5],acc[6],acc[7]);
    }
    __syncthreads();   // B2: GP reads of xin/y4 done AND xout visible
  }

  // ---- tail: blade-norm -> MLP -> loss ----
  float ss = 0.f;
  #pragma unroll
  for (int ii = 0; ii < 8; ++ii) ss = fmaf(acc[ii], acc[ii], ss);
  red[jo*64+f] = ss;
  __syncthreads();
  if (t < 64) {
    float s = 0.f;
    #pragma unroll
    for (int q = 0; q < 8; ++q) s += red[q*64+t];
    ynrm[t] = sqrtf(s);
  }
  __syncthreads();
  {
    float hp = 0.f;
    #pragma unroll
    for (int d = 0; d < 8; ++d) {
      const int f2 = 8*jo + d;
      hp = fmaf(w1t[f2*64+f], ynrm[f2], hp);   // coalesced (transposed)
    }
    red[jo*64+f] = hp;
  }
  __syncthreads();
  if (t < 64) {
    float hpre = mlp_b1[t];
    #pragma unroll
    for (int q = 0; q < 8; ++q) hpre += red[q*64+t];
    float h = hpre / (1.f + expf(-hpre));   // silu
    float p = h * mlp_w2[t];
    #pragma unroll
    for (int off = 32; off > 0; off >>= 1) p += __shfl_down(p, off, 64);
    if (t == 0 && wr) {
      float pred = p + mlp_b2[0];
      float d = pred - products[b];
      float loss = d*d;
      d_out[1+b] = loss;
      atomicAdd(d_out, loss * (1.f/256.f));
    }
  }
}

extern "C" void kernel_launch(void* const* d_in, const int* in_sizes, int n_in,
                              void* d_out, int out_size, void* d_ws, size_t ws_size,
                              hipStream_t stream) {
  const float* points   = (const float*)d_in[0];
  const float* products = (const float*)d_in[1];
  const float* lin_w    = (const float*)d_in[2];
  const float* lin_b    = (const float*)d_in[3];
  const float* gp_lin_w = (const float*)d_in[4];
  const float* gp_a     = (const float*)d_in[5];
  const float* gp_w     = (const float*)d_in[6];
  const float* mlp_w1   = (const float*)d_in[7];
  const float* mlp_b1   = (const float*)d_in[8];
  const float* mlp_w2   = (const float*)d_in[9];
  const float* mlp_b2   = (const float*)d_in[10];
  float* out = (float*)d_out;

  float* lw_t  = (float*)d_ws;        // 65536 floats
  float* gpw_t = lw_t + 65536;        // 16384 floats
  float* w1t   = gpw_t + 16384;       //  4096 floats

  ga_prep<<<336, 256, 0, stream>>>(gp_lin_w, gp_w, mlp_w1, lw_t, gpw_t, w1t, out);
  ga_main<<<2*NB, 512, 0, stream>>>(points, products, lin_w, lin_b, gp_a,
                                    mlp_b1, mlp_w2, mlp_b2,
                                    lw_t, gpw_t, w1t, out);
}

// Round 15
// 121.533 us; speedup vs baseline: 1.3381x; 1.3381x over previous
//
#include <hip/hip_runtime.h>

#define NB 256
#define IN_F 16
#define NGP 4

// ---------------- compile-time algebra tables (NATURAL blade order: idx=mask) ----
namespace alg {
constexpr int popc(int x){int c=0;while(x){c+=x&1;x>>=1;}return c;}
constexpr int qt(int m){return popc(m)&3;}
constexpr int sgn(int a,int b){int s=0;int t=a>>1;while(t){s+=popc(t&b);t>>=1;}return s&1;}
struct Tab {
  unsigned char w[64][64];   // [i][j] -> qt(i)*16 + qt(j)*4 + qt(i^j)
  unsigned char s[64][64];   // [i][j] -> sign of e_i * e_(i^j)
};
constexpr Tab build(){
  Tab t{};
  for(int i=0;i<64;++i)for(int j=0;j<64;++j){
    int k=i^j;
    t.w[i][j]=(unsigned char)(qt(i)*16+qt(j)*4+qt(k));
    t.s[i][j]=(unsigned char)sgn(i,k);
  }
  return t;
}
constexpr Tab T = build();
}

// ---------------- prep: transpose weights into workspace (coalesced READS) ----
// lw_t[((l*4+c)*64+m)*64+f] = gp_lin_w[((l*64+f)*64+m)*4+c]   (65536 floats)
// gpw_t[(l*64+widx)*64+f]   = gp_w[(l*64+f)*64+widx]          (16384 floats)
// w1t [f2*64+f]             = mlp_w1[f*64+f2]                 ( 4096 floats)
__global__ void ga_prep(const float* __restrict__ gp_lin_w,
                        const float* __restrict__ gp_w,
                        const float* __restrict__ mlp_w1,
                        float* __restrict__ lw_t, float* __restrict__ gpw_t,
                        float* __restrict__ w1t,
                        float* __restrict__ out) {
  const int bx = blockIdx.x, t = threadIdx.x;
  if (bx == 0 && t == 0) out[0] = 0.f;   // mean accumulator init
  if (bx < 256) {
    const int l = bx >> 6, f = bx & 63;
    const int m = t >> 2, c = t & 3;
    lw_t[((l*4+c)*64 + m)*64 + f] = gp_lin_w[bx*256 + t];
  } else if (bx < 320) {
    const int b2 = bx - 256;
    const int l = b2 >> 4, f0 = (b2 & 15) * 4;
    const int f = f0 + (t >> 6), k = t & 63;
    gpw_t[(l*64 + k)*64 + f] = gp_w[(l*64 + f0)*64 + t];
  } else {
    const int o = (bx - 320)*256 + t;
    const int f = o >> 6, f2 = o & 63;
    w1t[f2*64 + f] = mlp_w1[o];
  }
}

// ---------------- GP: interleaved j-octet over ic-pairs; all indices static ----
// x4/y4: [quad q][channel f][sub s]. (8p+a)^(8JO+b) = 8(p^JO)+(a^b) etc., so
// the pair {ic=2p, 2p+1} x both j-quads needs only y-quads {2(p^JO), +1}:
// 4 b128 reads feed 128 FMAs (the per-thread LDS-read floor). wv PRE-SCALED.
// FULLY unrolled: wv/acc indices must stay compile-time (R6/R12 law — any
// runtime index demotes the private array to scratch, ~200 MB WRITE_SIZE).
template<int JO>
__device__ __forceinline__ void gp_oct2(const float* __restrict__ x4,
    const float* __restrict__ y4, const float (&wv)[64], int f, float (&acc)[8]) {
  #pragma unroll
  for (int p = 0; p < 8; ++p) {
    const int r0 = 2*(p^JO);
    const float4 xv0 = *(const float4*)(x4 + ((2*p  )*64 + f)*4);
    const float4 xv1 = *(const float4*)(x4 + ((2*p+1)*64 + f)*4);
    const float4 yv0 = *(const float4*)(y4 + ((r0   )*64 + f)*4);
    const float4 yv1 = *(const float4*)(y4 + ((r0+1 )*64 + f)*4);
    const float x0[4] = {xv0.x,xv0.y,xv0.z,xv0.w};
    const float x1[4] = {xv1.x,xv1.y,xv1.z,xv1.w};
    const float y0[4] = {yv0.x,yv0.y,yv0.z,yv0.w};
    const float y1[4] = {yv1.x,yv1.y,yv1.z,yv1.w};
    #pragma unroll
    for (int b = 0; b < 4; ++b) {
      #pragma unroll
      for (int a = 0; a < 4; ++a) {
        const int i0 = 8*p + a, i1 = 8*p + 4 + a;
        const int j0 = 8*JO + b, j1 = 8*JO + 4 + b;
        float tp;
        tp = wv[alg::T.w[i0][j0]] * y0[a^b];   // k-quad r0
        acc[b]   = alg::T.s[i0][j0] ? fmaf(-tp, x0[a], acc[b])   : fmaf(tp, x0[a], acc[b]);
        tp = wv[alg::T.w[i1][j0]] * y1[a^b];   // k-quad r0+1
        acc[b]   = alg::T.s[i1][j0] ? fmaf(-tp, x1[a], acc[b])   : fmaf(tp, x1[a], acc[b]);
        tp = wv[alg::T.w[i0][j1]] * y1[a^b];   // k-quad r0+1
        acc[4+b] = alg::T.s[i0][j1] ? fmaf(-tp, x0[a], acc[4+b]) : fmaf(tp, x0[a], acc[4+b]);
        tp = wv[alg::T.w[i1][j1]] * y0[a^b];   // k-quad r0
        acc[4+b] = alg::T.s[i1][j1] ? fmaf(-tp, x1[a], acc[4+b]) : fmaf(tp, x1[a], acc[4+b]);
      }
    }
  }
}

// ---------------- main fused kernel: one 512-thread block per batch element ----
// R11 optimum, reverted after R12/R13/R14 falsifications. Structure notes:
// - LDS 57984 B in the (53.3, 80) KB window -> 2-block/CU budget -> 128 VGPR
//   (R1..R13 allocator model). 128 VGPR x 4 waves/SIMD = the whole register
//   file -> a second co-resident block never fits (R14) -> 2 waves/SIMD is
//   the hardware-forced occupancy for this register demand.
// - Double-buffered x (xA/xB) -> 2 barriers/layer (R11 win).
// - Unroll law (R6/R12): loops indexing private arrays with the loop counter
//   (norm s4, wv build, GP) must be FULLY unrolled; partial unroll demotes
//   them to scratch (~200 MB WRITE_SIZE, 3x regression).
__global__ __launch_bounds__(512) void ga_main(
    const float* __restrict__ points, const float* __restrict__ products,
    const float* __restrict__ lin_w,  const float* __restrict__ lin_b,
    const float* __restrict__ gp_a,
    const float* __restrict__ mlp_b1,
    const float* __restrict__ mlp_w2, const float* __restrict__ mlp_b2,
    const float* __restrict__ lw_t,   const float* __restrict__ gpw_t,
    const float* __restrict__ w1t,
    float* __restrict__ d_out)
{
  __shared__ __align__(16) float xA[16*64*4];  // state buf A [quad][f][sub] (16384 B)
  __shared__ __align__(16) float xB[16*64*4];  // state buf B               (16384 B)
  __shared__ __align__(16) float y4[16*64*4];  // lin out    [quad][f][sub] (16384 B)
  __shared__ float red[4*8*64];                // tail partials              (8192 B)
  __shared__ float pts[96];                    //                            ( 384 B)
  __shared__ float ynrm[64];                   //                            ( 256 B)

  const int t  = threadIdx.x;
  const int b  = blockIdx.x;
  const int f  = t & 63;
  const int jo = t >> 6;                       // 0..7, wave-uniform
  const int qb = __builtin_popcount((unsigned)jo) & 3;

  for (int i = t; i < 16*64*4; i += 512) xA[i] = 0.f;
  if (t < 96) pts[t] = points[b*96 + t];
  __syncthreads();

  // phase 0: embed grade-1 + first qt-linear (blades {0,1,2,4,8,16,32} nonzero)
  if (t < 64) {
    float a[6] = {0,0,0,0,0,0};
    for (int m = 0; m < IN_F; ++m) {
      float lw = lin_w[(t*IN_F+m)*4 + 1];   // qt(grade1)=1
      #pragma unroll
      for (int g = 0; g < 6; ++g) a[g] = fmaf(pts[m*6+g], lw, a[g]);
    }
    xA[(0*64+t)*4+0] = lin_b[t];   // blade 0
    xA[(0*64+t)*4+1] = a[0];       // blade 1
    xA[(0*64+t)*4+2] = a[1];       // blade 2
    xA[(1*64+t)*4+0] = a[2];       // blade 4
    xA[(2*64+t)*4+0] = a[3];       // blade 8
    xA[(4*64+t)*4+0] = a[4];       // blade 16
    xA[(8*64+t)*4+0] = a[5];       // blade 32
  }
  __syncthreads();

  float acc[8];

  for (int l = 0; l < NGP; ++l) {
    const float* xin  = (l & 1) ? xB : xA;
    float*       xout = (l & 1) ? xA : xB;

    // ---- qt-linear: 8 outputs/thread (j = 8*jo+d); classes qb+{0,1,1,2,1,2,2,3}
    {
      float lacc[8] = {0,0,0,0,0,0,0,0};
      const float* pA = lw_t + (l*4 + ((qb+0)&3))*4096 + f;
      const float* pB = lw_t + (l*4 + ((qb+1)&3))*4096 + f;
      const float* pC = lw_t + (l*4 + ((qb+2)&3))*4096 + f;
      const float* pD = lw_t + (l*4 + ((qb+3)&3))*4096 + f;
      #pragma unroll 8
      for (int m = 0; m < 64; ++m) {
        const float4 xq0 = *(const float4*)(xin + ((2*jo  )*64 + m)*4); // broadcast
        const float4 xq1 = *(const float4*)(xin + ((2*jo+1)*64 + m)*4); // broadcast
        const float wA = pA[m*64], wB = pB[m*64], wC = pC[m*64], wD = pD[m*64];
        lacc[0] = fmaf(wA, xq0.x, lacc[0]);
        lacc[1] = fmaf(wB, xq0.y, lacc[1]);
        lacc[2] = fmaf(wB, xq0.z, lacc[2]);
        lacc[3] = fmaf(wC, xq0.w, lacc[3]);
        lacc[4] = fmaf(wB, xq1.x, lacc[4]);
        lacc[5] = fmaf(wC, xq1.y, lacc[5]);
        lacc[6] = fmaf(wC, xq1.z, lacc[6]);
        lacc[7] = fmaf(wD, xq1.w, lacc[7]);
      }
      // y-store (b128, RAW — normalization folded into wv later)
      *(float4*)(y4 + ((2*jo  )*64 + f)*4) = make_float4(lacc[0],lacc[1],lacc[2],lacc[3]);
      *(float4*)(y4 + ((2*jo+1)*64 + f)*4) = make_float4(lacc[4],lacc[5],lacc[6],lacc[7]);
    }
    __syncthreads();   // B1: y4 complete

    // ---- self-computed norms (redundant per thread; no reduction barriers) ----
    // FULLY unrolled: qc must be compile-time (s4 indexing).
    float iv[4];
    {
      float s4[4] = {0.f, 0.f, 0.f, 0.f};
      #pragma unroll
      for (int q = 0; q < 16; ++q) {
        const float4 yv = *(const float4*)(y4 + (q*64 + f)*4);
        const int qc = alg::popc(q) & 3;   // compile-time per unrolled q
        s4[(qc+0)&3] = fmaf(yv.x, yv.x, s4[(qc+0)&3]);
        s4[(qc+1)&3] = fmaf(yv.y, yv.y, s4[(qc+1)&3]);
        s4[(qc+1)&3] = fmaf(yv.z, yv.z, s4[(qc+1)&3]);
        s4[(qc+2)&3] = fmaf(yv.w, yv.w, s4[(qc+2)&3]);
      }
      #pragma unroll
      for (int c = 0; c < 4; ++c) {
        const float nrm = sqrtf(fmaxf(s4[c], 1e-12f));
        const float av  = gp_a[(l*64+f)*4 + c];
        const float sig = 1.f/(1.f + expf(-av));
        const float nn  = sig*(nrm-1.f) + 1.f;
        iv[c] = 1.f/(nn + 1e-6f);
      }
    }

    // ---- weight table: coalesced b32 loads, PRE-SCALED by invn (qk = wi&3) ----
    float wv[64];
    {
      const float* gw = gpw_t + l*4096 + f;   // [widx][f], coalesced
      #pragma unroll
      for (int wq = 0; wq < 16; ++wq) {
        wv[wq*4+0] = gw[(wq*4+0)*64] * iv[0];
        wv[wq*4+1] = gw[(wq*4+1)*64] * iv[1];
        wv[wq*4+2] = gw[(wq*4+2)*64] * iv[2];
        wv[wq*4+3] = gw[(wq*4+3)*64] * iv[3];
      }
    }

    // ---- geometric product: interleaved octet, writes the OTHER x buffer ----
    #pragma unroll
    for (int ii = 0; ii < 8; ++ii) acc[ii] = 0.f;
    switch (jo) {
      case 0: gp_oct2<0>(xin, y4, wv, f, acc); break;
      case 1: gp_oct2<1>(xin, y4, wv, f, acc); break;
      case 2: gp_oct2<2>(xin, y4, wv, f, acc); break;
      case 3: gp_oct2<3>(xin, y4, wv, f, acc); break;
      case 4: gp_oct2<4>(xin, y4, wv, f, acc); break;
      case 5: gp_oct2<5>(xin, y4, wv, f, acc); break;
      case 6: gp_oct2<6>(xin, y4, wv, f, acc); break;
      default: gp_oct2<7>(xin, y4, wv, f, acc); break;
    }
    if (l < NGP-1) {
      *(float4*)(xout + ((2*jo  )*64 + f)*4) = make_float4(acc[0],acc[1],acc[2],acc[3]);
      *(float4*)(xout + ((2*jo+1)*64 + f)*4) = make_float4(acc[4],acc[5],acc[6],acc[7]);
    }
    __syncthreads();   // B2: GP reads of xin/y4 done AND xout visible
  }

  // ---- tail: blade-norm -> MLP -> loss ----
  float ss = 0.f;
  #pragma unroll
  for (int ii = 0; ii < 8; ++ii) ss = fmaf(acc[ii], acc[ii], ss);
  red[jo*64+f] = ss;
  __syncthreads();
  if (t < 64) {
    float s = 0.f;
    #pragma unroll
    for (int q = 0; q < 8; ++q) s += red[q*64+t];
    ynrm[t] = sqrtf(s);
  }
  __syncthreads();
  {
    float hp = 0.f;
    #pragma unroll
    for (int d = 0; d < 8; ++d) {
      const int f2 = 8*jo + d;
      hp = fmaf(w1t[f2*64+f], ynrm[f2], hp);   // coalesced (transposed)
    }
    red[jo*64+f] = hp;
  }
  __syncthreads();
  if (t < 64) {
    float hpre = mlp_b1[t];
    #pragma unroll
    for (int q = 0; q < 8; ++q) hpre += red[q*64+t];
    float h = hpre / (1.f + expf(-hpre));   // silu
    float p = h * mlp_w2[t];
    #pragma unroll
    for (int off = 32; off > 0; off >>= 1) p += __shfl_down(p, off, 64);
    if (t == 0) {
      float pred = p + mlp_b2[0];
      float d = pred - products[b];
      float loss = d*d;
      d_out[1+b] = loss;
      atomicAdd(d_out, loss * (1.f/256.f));
    }
  }
}

extern "C" void kernel_launch(void* const* d_in, const int* in_sizes, int n_in,
                              void* d_out, int out_size, void* d_ws, size_t ws_size,
                              hipStream_t stream) {
  const float* points   = (const float*)d_in[0];
  const float* products = (const float*)d_in[1];
  const float* lin_w    = (const float*)d_in[2];
  const float* lin_b    = (const float*)d_in[3];
  const float* gp_lin_w = (const float*)d_in[4];
  const float* gp_a     = (const float*)d_in[5];
  const float* gp_w     = (const float*)d_in[6];
  const float* mlp_w1   = (const float*)d_in[7];
  const float* mlp_b1   = (const float*)d_in[8];
  const float* mlp_w2   = (const float*)d_in[9];
  const float* mlp_b2   = (const float*)d_in[10];
  float* out = (float*)d_out;

  float* lw_t  = (float*)d_ws;        // 65536 floats
  float* gpw_t = lw_t + 65536;        // 16384 floats
  float* w1t   = gpw_t + 16384;       //  4096 floats

  ga_prep<<<336, 256, 0, stream>>>(gp_lin_w, gp_w, mlp_w1, lw_t, gpw_t, w1t, out);
  ga_main<<<NB, 512, 0, stream>>>(points, products, lin_w, lin_b, gp_a,
                                  mlp_b1, mlp_w2, mlp_b2,
                                  lw_t, gpw_t, w1t, out);
}